// Round 4
// baseline (420.302 us; speedup 1.0000x reference)
//
#include <hip/hip_runtime.h>

namespace {
constexpr int kB = 256;
constexpr int kT = 1024;
constexpr int kS = 96;
constexpr int kStart = 1;
constexpr float kCF = 3.5f;   // keeps exp-space growth ~e^0/step
constexpr float kLn2 = 0.69314718055994531f;

// ws float layout
constexpr int OFF_PF  = 0;                  // [kB][kS] forward p_H
constexpr int OFF_WB  = kB * kS;            // [kB][kS] backward w_H
constexpr int OFF_LF  = 2 * kB * kS;        // [kB]
constexpr int OFF_LB  = OFF_LF + kB;        // [kB]
constexpr int OFF_NUM = OFF_LB + kB;        // [kB]

// One chain step. Single wave => no barrier; compiler orders LDS ops with
// lgkmcnt. Unified fwd/bwd: body = [apply-exp-pre(bwd) | write p | broadcast
// read | dot | apply-exp-post(fwd) | mask-select | optional renorm].
template <bool RN>
__device__ __forceinline__ void chain_step(
    bool bwd, float fav, float fbv, float mkv,
    float& pownA, float& pownB, float& Lacc,
    float* pl, const float* wA, const float* wB2, int l, int half) {
  const float efA = __expf(fav - kCF);
  const float efB = __expf(fbv - kCF);
  pl[l] = bwd ? pownA * efA : pownA;
  if (l < 32) pl[64 + l] = bwd ? pownB * efB : pownB;

  // full row dot (row l): 24 same-address float4 broadcasts
  float a0 = 0.f, a1 = 0.f, a2 = 0.f, a3 = 0.f;
  const float4* pc = (const float4*)pl;
#pragma unroll
  for (int c = 0; c < 24; ++c) {
    const float4 pv = pc[c];
    a0 = fmaf(wA[4 * c + 0], pv.x, a0);
    a1 = fmaf(wA[4 * c + 1], pv.y, a1);
    a2 = fmaf(wA[4 * c + 2], pv.z, a2);
    a3 = fmaf(wA[4 * c + 3], pv.w, a3);
  }
  // half of row 64+(l&31): lane's 12 chunks (2 distinct addrs/wave, no conflict)
  float b0 = 0.f, b1 = 0.f, b2 = 0.f, b3 = 0.f;
  const float4* pq = pc + half * 12;
#pragma unroll
  for (int c = 0; c < 12; ++c) {
    const float4 pv = pq[c];
    b0 = fmaf(wB2[4 * c + 0], pv.x, b0);
    b1 = fmaf(wB2[4 * c + 1], pv.y, b1);
    b2 = fmaf(wB2[4 * c + 2], pv.z, b2);
    b3 = fmaf(wB2[4 * c + 3], pv.w, b3);
  }
  float accA = (a0 + a1) + (a2 + a3);
  float accB = (b0 + b1) + (b2 + b3);
  accB += __shfl_xor(accB, 32, 64);   // both halves get full row-64+k sum

  float pnA = bwd ? accA : accA * efA;
  float pnB = bwd ? accB : accB * efB;
  pnA = (mkv > 0.f) ? pnA : pownA;
  pnB = (mkv > 0.f) ? pnB : pownB;

  if (RN) {   // every 8th step: exact power-of-2 rescale from wave max
    float m = fmaxf(pnA, pnB);
#pragma unroll
    for (int off = 32; off; off >>= 1) m = fmaxf(m, __shfl_xor(m, off, 64));
    const int e = (__float_as_int(m) >> 23) & 0xFF;
    const float sc = __int_as_float((254 - e) << 23);   // 2^(127-e)
    Lacc += (float)(e - 127) * kLn2;
    pnA *= sc;
    pnB *= sc;
  }
  pownA = pnA;
  pownB = pnB;
}

// grid: [0,256) fwd chains, [256,512) bwd chains, [512,768) numerator blocks.
__global__ __launch_bounds__(64, 1) void crf_main(
    const float* __restrict__ F, const int* __restrict__ states,
    const float* __restrict__ mask, const float* __restrict__ trans,
    float* __restrict__ ws) {
  const int bid = blockIdx.x;
  const int l = threadIdx.x;

  if (bid >= 2 * kB) {   // ---- numerator block (fills idle SIMDs) ----
    const int b = bid - 2 * kB;
    const int* st = states + b * kT;
    const float* Fb = F + (size_t)b * kT * kS;
    const float* mb = mask + b * kT;
    float acc = 0.f;
    for (int t = l; t < kT; t += 64) {
      const int cu = st[t];
      const int pr = (t > 0) ? st[t - 1] : kStart;
      acc += (Fb[(size_t)t * kS + cu] + trans[cu * kS + pr]) * mb[t];
    }
#pragma unroll
    for (int off = 32; off; off >>= 1) acc += __shfl_xor(acc, off, 64);
    if (l == 0) ws[OFF_NUM + b] = acc;
    return;
  }

  const bool bwd = bid >= kB;
  const int b = bwd ? bid - kB : bid;
  const int k = l & 31;
  const int half = l >> 5;

  __shared__ __align__(16) float pl[kS];
  __shared__ __align__(16) float ml[kT];

  const float* Fb = F + (size_t)b * kT * kS;

  // matrix fragments in registers: fwd = M rows, bwd = M^T rows (M columns)
  float wA[96], wB2[48];
  if (!bwd) {
#pragma unroll
    for (int c = 0; c < 24; ++c) {
      const float4 tv = ((const float4*)(trans + l * kS))[c];
      wA[4 * c + 0] = __expf(tv.x - kCF);
      wA[4 * c + 1] = __expf(tv.y - kCF);
      wA[4 * c + 2] = __expf(tv.z - kCF);
      wA[4 * c + 3] = __expf(tv.w - kCF);
    }
#pragma unroll
    for (int c = 0; c < 12; ++c) {
      const float4 tv = ((const float4*)(trans + (64 + k) * kS + half * 48))[c];
      wB2[4 * c + 0] = __expf(tv.x - kCF);
      wB2[4 * c + 1] = __expf(tv.y - kCF);
      wB2[4 * c + 2] = __expf(tv.z - kCF);
      wB2[4 * c + 3] = __expf(tv.w - kCF);
    }
  } else {
#pragma unroll
    for (int j = 0; j < 96; ++j) wA[j] = __expf(trans[j * kS + l] - kCF);
#pragma unroll
    for (int jj = 0; jj < 48; ++jj)
      wB2[jj] = __expf(trans[(half * 48 + jj) * kS + 64 + k] - kCF);
  }

  {  // stage mask row once (single wave -> no barrier)
    const float4* mb4 = (const float4*)(mask + (size_t)b * kT);
    float4* ml4 = (float4*)ml;
#pragma unroll
    for (int q = 0; q < 4; ++q) ml4[l + 64 * q] = mb4[l + 64 * q];
  }

  float pownA = bwd ? 1.f : (l == kStart ? 1.f : 0.f);
  float pownB = bwd ? 1.f : 0.f;
  float Lacc = 0.f;

  // feature prefetch, 8 steps deep, straight into registers
  float fa[8], fb[8];
#pragma unroll
  for (int q = 0; q < 8; ++q) {
    const int t = bwd ? (kT - 1 - q) : q;
    const float* ft = Fb + (size_t)t * kS;
    fa[q] = ft[l];
    fb[q] = ft[64 + k];
  }

  for (int it = 0; it < 64; ++it) {
#pragma unroll
    for (int q = 0; q < 8; ++q) {
      const int s = it * 8 + q;
      const float fau = fa[q], fbu = fb[q];
      int ps = s + 8;
      ps = ps > 511 ? 511 : ps;   // clamp: dead loads at tail, never OOB
      const int tp = bwd ? (kT - 1 - ps) : ps;
      const float* ft = Fb + (size_t)tp * kS;
      fa[q] = ft[l];
      fb[q] = ft[64 + k];
      const int t = bwd ? (kT - 1 - s) : s;
      const float mkv = ml[t];
      if (q == 7)
        chain_step<true>(bwd, fau, fbu, mkv, pownA, pownB, Lacc, pl, wA, wB2, l, half);
      else
        chain_step<false>(bwd, fau, fbu, mkv, pownA, pownB, Lacc, pl, wA, wB2, l, half);
    }
  }

  float* dst = ws + (bwd ? OFF_WB : OFF_PF) + b * kS;
  dst[l] = pownA;
  if (l < 32) dst[64 + l] = pownB;
  if (l == 0) ws[(bwd ? OFF_LB : OFF_LF) + b] = Lacc;
}

// combine halves: out = LF + LB + log(dot(p_F, w_B)) - numerator
__global__ __launch_bounds__(64) void crf_finalize(
    const float* __restrict__ ws, float* __restrict__ out) {
  const int b = blockIdx.x;
  const int l = threadIdx.x;
  float d = ws[OFF_PF + b * kS + l] * ws[OFF_WB + b * kS + l];
  if (l < 32)
    d += ws[OFF_PF + b * kS + 64 + l] * ws[OFF_WB + b * kS + 64 + l];
#pragma unroll
  for (int off = 32; off; off >>= 1) d += __shfl_xor(d, off, 64);
  if (l == 0)
    out[b] = (ws[OFF_LF + b] + ws[OFF_LB + b] + logf(d)) - ws[OFF_NUM + b];
}
} // namespace

extern "C" void kernel_launch(void* const* d_in, const int* in_sizes, int n_in,
                              void* d_out, int out_size, void* d_ws, size_t ws_size,
                              hipStream_t stream) {
  const float* F      = (const float*)d_in[0];
  const int*   states = (const int*)d_in[1];
  const float* mask   = (const float*)d_in[2];
  const float* trans  = (const float*)d_in[3];
  float* out = (float*)d_out;
  float* ws  = (float*)d_ws;
  hipLaunchKernelGGL(crf_main, dim3(3 * kB), dim3(64), 0, stream,
                     F, states, mask, trans, ws);
  hipLaunchKernelGGL(crf_finalize, dim3(kB), dim3(64), 0, stream, ws, out);
}